// Round 1
// baseline (327.144 us; speedup 1.0000x reference)
//
#include <hip/hip_runtime.h>
#include <math.h>

// GAT 2-layer: N=10000, E=160000 (+N self loops), IN=128, H1=8, C1=128, OUT=64.
// Strategy: build CSR (edges grouped by dst) once per launch, then
// gather-based aggregation (no scatter atomics on the wide accumulators).

#define NEG_SLOPE 0.2f

__device__ __forceinline__ float leaky(float v) { return v >= 0.0f ? v : NEG_SLOPE * v; }

// ---------------- CSR build ----------------

__global__ void count_kernel(const int* __restrict__ ei, int* __restrict__ counts, int E, int N) {
    int i = blockIdx.x * blockDim.x + threadIdx.x;
    int M = E + N;
    if (i >= M) return;
    int dst = (i < E) ? ei[E + i] : (i - E);   // self-loop tail
    atomicAdd(&counts[dst], 1);
}

// single-block exclusive scan over N counts -> offsets[N+1], cursor copy
__global__ void scan_kernel(const int* __restrict__ counts, int* __restrict__ offsets,
                            int* __restrict__ cursor, int N) {
    __shared__ int sm[1024];
    __shared__ int carry;
    int t = threadIdx.x;
    if (t == 0) carry = 0;
    __syncthreads();
    for (int base = 0; base < N; base += 1024) {
        int idx = base + t;
        int v = (idx < N) ? counts[idx] : 0;
        sm[t] = v;
        __syncthreads();
        int acc = v;
        for (int off = 1; off < 1024; off <<= 1) {
            int other = (t >= off) ? sm[t - off] : 0;
            __syncthreads();
            acc += other;
            sm[t] = acc;
            __syncthreads();
        }
        int excl = acc - v;
        int c = carry;
        if (idx < N) { offsets[idx] = c + excl; cursor[idx] = c + excl; }
        __syncthreads();
        if (t == 1023) carry = c + acc;   // acc of last thread = chunk total (inclusive)
        __syncthreads();
    }
    if (t == 0) offsets[N] = carry;
}

__global__ void fill_kernel(const int* __restrict__ ei, int* __restrict__ cursor,
                            int* __restrict__ srcs, int E, int N) {
    int i = blockIdx.x * blockDim.x + threadIdx.x;
    int M = E + N;
    if (i >= M) return;
    int src, dst;
    if (i < E) { src = ei[i]; dst = ei[E + i]; }
    else       { src = dst = i - E; }
    int pos = atomicAdd(&cursor[dst], 1);
    srcs[pos] = src;
}

// ---------------- Layer 1 transform: h1 = x @ W1, alpha_s/alpha_d ----------------
// 8 nodes per block, 256 threads. Each thread owns 4 output channels (one head).

__global__ __launch_bounds__(256) void l1_transform(
    const float* __restrict__ x, const float* __restrict__ W1,
    const float* __restrict__ a_src1, const float* __restrict__ a_dst1,
    float* __restrict__ h1, float* __restrict__ as1, float* __restrict__ ad1, int N) {
    int nb = blockIdx.x * 8;
    int t = threadIdx.x;
    __shared__ float xs[8 * 128];
    {
        int li = t * 4;
        int node = nb + (li >> 7);
        float4 xv = make_float4(0.f, 0.f, 0.f, 0.f);
        if (node < N) xv = *(const float4*)(x + (size_t)nb * 128 + li);
        *(float4*)(xs + li) = xv;
    }
    __syncthreads();
    int c0 = t * 4;           // output channel 0..1023
    int h = t >> 5;           // head 0..7 (128 ch per head)
    float4 acc[8];
#pragma unroll
    for (int nd = 0; nd < 8; nd++) acc[nd] = make_float4(0.f, 0.f, 0.f, 0.f);
    for (int k = 0; k < 128; k++) {
        float4 w = *(const float4*)(W1 + (size_t)k * 1024 + c0);
#pragma unroll
        for (int nd = 0; nd < 8; nd++) {
            float xk = xs[nd * 128 + k];
            acc[nd].x = fmaf(xk, w.x, acc[nd].x);
            acc[nd].y = fmaf(xk, w.y, acc[nd].y);
            acc[nd].z = fmaf(xk, w.z, acc[nd].z);
            acc[nd].w = fmaf(xk, w.w, acc[nd].w);
        }
    }
    float4 asv = *(const float4*)(a_src1 + h * 128 + (c0 & 127));
    float4 adv = *(const float4*)(a_dst1 + h * 128 + (c0 & 127));
#pragma unroll
    for (int nd = 0; nd < 8; nd++) {
        int n = nb + nd;
        float4 a = acc[nd];
        float ps = a.x * asv.x + a.y * asv.y + a.z * asv.z + a.w * asv.w;
        float pd = a.x * adv.x + a.y * adv.y + a.z * adv.z + a.w * adv.w;
        // reduce over the 32 threads of this head (within a 32-lane half-wave)
#pragma unroll
        for (int mm = 16; mm >= 1; mm >>= 1) {
            ps += __shfl_xor(ps, mm);
            pd += __shfl_xor(pd, mm);
        }
        if (n < N) {
            *(float4*)(h1 + (size_t)n * 1024 + c0) = a;
            if ((t & 31) == 0) { as1[n * 8 + h] = ps; ad1[n * 8 + h] = pd; }
        }
    }
}

// ---------------- Layer 1 aggregate: segment softmax + weighted gather + bias + ELU ----

__global__ __launch_bounds__(256) void l1_agg(
    const float* __restrict__ h1, const float* __restrict__ as1, const float* __restrict__ ad1,
    const float* __restrict__ b1, const int* __restrict__ offsets, const int* __restrict__ srcs,
    float* __restrict__ hbuf, int N) {
    int n = blockIdx.x;
    int t = threadIdx.x;
    int beg = offsets[n];
    int deg = offsets[n + 1] - beg;
    __shared__ float ad[8], mh[8], sh[8];
    __shared__ float red[256];
    if (t < 8) ad[t] = ad1[n * 8 + t];
    __syncthreads();
    // --- per-head max over incoming edges: 8 heads x 32 edge-lanes ---
    int h = t & 7, el = t >> 3;
    float m = -3.4e38f;
    for (int i = el; i < deg; i += 32) {
        int s = srcs[beg + i];
        m = fmaxf(m, leaky(as1[s * 8 + h] + ad[h]));
    }
    red[t] = m;
    __syncthreads();
    for (int off = 128; off >= 8; off >>= 1) {
        if (t < off) red[t] = fmaxf(red[t], red[t + off]);
        __syncthreads();
    }
    if (t < 8) mh[t] = red[t];
    __syncthreads();
    // --- weighted accumulate: thread owns channels c0..c0+3 (head hh) ---
    int c0 = t * 4;
    int hh = t >> 5;
    float mhh = mh[hh], adh = ad[hh];
    float ax = 0.f, ay = 0.f, az = 0.f, aw = 0.f, ssum = 0.f;
    for (int i = 0; i < deg; i++) {
        int s = srcs[beg + i];
        float w = __expf(leaky(as1[s * 8 + hh] + adh) - mhh);
        float4 hv = *(const float4*)(h1 + (size_t)s * 1024 + c0);
        ax = fmaf(w, hv.x, ax);
        ay = fmaf(w, hv.y, ay);
        az = fmaf(w, hv.z, az);
        aw = fmaf(w, hv.w, aw);
        ssum += w;
    }
    if ((t & 31) == 0) sh[hh] = ssum;   // t = 32*hh
    __syncthreads();
    float inv = 1.0f / (sh[hh] + 1e-16f);
    float4 bv = *(const float4*)(b1 + c0);
    float ox = ax * inv + bv.x;
    float oy = ay * inv + bv.y;
    float oz = az * inv + bv.z;
    float ow = aw * inv + bv.w;
    // ELU
    ox = ox > 0.f ? ox : expm1f(ox);
    oy = oy > 0.f ? oy : expm1f(oy);
    oz = oz > 0.f ? oz : expm1f(oz);
    ow = ow > 0.f ? ow : expm1f(ow);
    *(float4*)(hbuf + (size_t)n * 1024 + c0) = make_float4(ox, oy, oz, ow);
}

// ---------------- Layer 2 transform: h2 = hbuf @ W2, alpha_s2/alpha_d2 ----------------
// 8 nodes per block, 256 threads: thread computes channel t&63 over k-range (t>>6)*256.

__global__ __launch_bounds__(256) void l2_transform(
    const float* __restrict__ hbuf, const float* __restrict__ W2,
    const float* __restrict__ a_src2, const float* __restrict__ a_dst2,
    float* __restrict__ h2, float* __restrict__ as2, float* __restrict__ ad2, int N) {
    int nb = blockIdx.x * 8;
    int t = threadIdx.x;
    __shared__ float hs[8 * 1024];
#pragma unroll
    for (int j = 0; j < 8; j++) {
        int idx = j * 1024 + t * 4;
        float4 v = make_float4(0.f, 0.f, 0.f, 0.f);
        if (nb + j < N) v = *(const float4*)(hbuf + (size_t)nb * 1024 + idx);
        *(float4*)(hs + idx) = v;
    }
    __syncthreads();
    int c = t & 63, kb = t >> 6;
    float acc[8];
#pragma unroll
    for (int nd = 0; nd < 8; nd++) acc[nd] = 0.f;
    for (int j = 0; j < 256; j++) {
        int k = kb * 256 + j;
        float w = W2[(size_t)k * 64 + c];
#pragma unroll
        for (int nd = 0; nd < 8; nd++) acc[nd] = fmaf(hs[nd * 1024 + k], w, acc[nd]);
    }
    __shared__ float red[256];
    for (int nd = 0; nd < 8; nd++) {
        red[t] = acc[nd];
        __syncthreads();
        if (t < 128) red[t] += red[t + 128];
        __syncthreads();
        if (t < 64) {
            float v = red[t] + red[t + 64];
            int n = nb + nd;
            float ps = v * a_src2[t];
            float pd = v * a_dst2[t];
#pragma unroll
            for (int mm = 32; mm >= 1; mm >>= 1) {
                ps += __shfl_xor(ps, mm);
                pd += __shfl_xor(pd, mm);
            }
            if (n < N) {
                h2[(size_t)n * 64 + t] = v;
                if (t == 0) { as2[n] = ps; ad2[n] = pd; }
            }
        }
        __syncthreads();
    }
}

// ---------------- Layer 2 aggregate ----------------

__global__ __launch_bounds__(256) void l2_agg(
    const float* __restrict__ h2, const float* __restrict__ as2, const float* __restrict__ ad2,
    const float* __restrict__ b2, const int* __restrict__ offsets, const int* __restrict__ srcs,
    float* __restrict__ out, int N) {
    int n = blockIdx.x;
    int t = threadIdx.x;
    int beg = offsets[n];
    int deg = offsets[n + 1] - beg;
    __shared__ float red[256];
    __shared__ float sarr[4];
    __shared__ float m_sh;
    float adn = ad2[n];
    float m = -3.4e38f;
    for (int i = t; i < deg; i += 256) m = fmaxf(m, leaky(as2[srcs[beg + i]] + adn));
    red[t] = m;
    __syncthreads();
    for (int off = 128; off >= 1; off >>= 1) {
        if (t < off) red[t] = fmaxf(red[t], red[t + off]);
        __syncthreads();
    }
    if (t == 0) m_sh = red[0];
    __syncthreads();
    float mv = m_sh;
    int c = t & 63, eg = t >> 6;
    float acc = 0.f, ssum = 0.f;
    for (int i = eg; i < deg; i += 4) {
        int s = srcs[beg + i];
        float w = __expf(leaky(as2[s] + adn) - mv);
        acc = fmaf(w, h2[(size_t)s * 64 + c], acc);
        ssum += w;
    }
    __syncthreads();   // red reuse
    red[t] = acc;
    if (c == 0) sarr[eg] = ssum;
    __syncthreads();
    if (t < 128) red[t] += red[t + 128];
    __syncthreads();
    if (t < 64) {
        float v = red[t] + red[t + 64];
        float s = sarr[0] + sarr[1] + sarr[2] + sarr[3] + 1e-16f;
        out[(size_t)n * 64 + t] = v / s + b2[t];
    }
}

// ---------------- launch ----------------

static inline size_t align_up(size_t v, size_t a) { return (v + a - 1) / a * a; }

extern "C" void kernel_launch(void* const* d_in, const int* in_sizes, int n_in,
                              void* d_out, int out_size, void* d_ws, size_t ws_size,
                              hipStream_t stream) {
    const float* x      = (const float*)d_in[0];
    const int*   ei     = (const int*)d_in[1];
    const float* W1     = (const float*)d_in[2];
    const float* a_src1 = (const float*)d_in[3];
    const float* a_dst1 = (const float*)d_in[4];
    const float* b1     = (const float*)d_in[5];
    const float* W2     = (const float*)d_in[6];
    const float* a_src2 = (const float*)d_in[7];
    const float* a_dst2 = (const float*)d_in[8];
    const float* b2     = (const float*)d_in[9];
    float* out = (float*)d_out;

    int N = in_sizes[0] / 128;
    int E = in_sizes[1] / 2;
    int M = E + N;

    // workspace carve (all 256B-aligned)
    char* p = (char*)d_ws;
    size_t off = 0;
    auto carve = [&](size_t bytes) {
        void* r = p + off;
        off = align_up(off + bytes, 256);
        return r;
    };
    int*   counts  = (int*)carve((size_t)N * 4);
    int*   offsets = (int*)carve((size_t)(N + 1) * 4);
    int*   cursor  = (int*)carve((size_t)N * 4);
    int*   srcs    = (int*)carve((size_t)M * 4);
    float* as1     = (float*)carve((size_t)N * 8 * 4);
    float* ad1     = (float*)carve((size_t)N * 8 * 4);
    float* as2     = (float*)carve((size_t)N * 4);
    float* ad2     = (float*)carve((size_t)N * 4);
    float* h2      = (float*)carve((size_t)N * 64 * 4);
    float* h1      = (float*)carve((size_t)N * 1024 * 4);
    float* hbuf    = (float*)carve((size_t)N * 1024 * 4);
    (void)ws_size; // needs ~86 MB

    hipMemsetAsync(counts, 0, (size_t)N * 4, stream);
    count_kernel<<<(M + 255) / 256, 256, 0, stream>>>(ei, counts, E, N);
    scan_kernel<<<1, 1024, 0, stream>>>(counts, offsets, cursor, N);
    fill_kernel<<<(M + 255) / 256, 256, 0, stream>>>(ei, cursor, srcs, E, N);
    l1_transform<<<(N + 7) / 8, 256, 0, stream>>>(x, W1, a_src1, a_dst1, h1, as1, ad1, N);
    l1_agg<<<N, 256, 0, stream>>>(h1, as1, ad1, b1, offsets, srcs, hbuf, N);
    l2_transform<<<(N + 7) / 8, 256, 0, stream>>>(hbuf, W2, a_src2, a_dst2, h2, as2, ad2, N);
    l2_agg<<<N, 256, 0, stream>>>(h2, as2, ad2, b2, offsets, srcs, out, N);
}

// Round 2
// 300.754 us; speedup vs baseline: 1.0877x; 1.0877x over previous
//
#include <hip/hip_runtime.h>
#include <math.h>

// GAT 2-layer: N=10000, E=160000 (+N self loops), IN=128, H1=8, C1=128, OUT=64.
// CSR build (grouped by dst) then gather-based aggregation.
// R2: LDS-staged softmax weights in agg kernels, 16-node l1_transform,
//     work-efficient scan, single-sync l2_transform reduction.

#define NEG_SLOPE 0.2f

__device__ __forceinline__ float leaky(float v) { return v >= 0.0f ? v : NEG_SLOPE * v; }

// ---------------- CSR build ----------------

__global__ void count_kernel(const int* __restrict__ ei, int* __restrict__ counts, int E, int N) {
    int i = blockIdx.x * blockDim.x + threadIdx.x;
    int M = E + N;
    if (i >= M) return;
    int dst = (i < E) ? ei[E + i] : (i - E);   // self-loop tail
    atomicAdd(&counts[dst], 1);
}

// single-block work-efficient scan: thread-serial sums + 1024-wide Hillis-Steele
__global__ __launch_bounds__(1024) void scan_kernel(
    const int* __restrict__ counts, int* __restrict__ offsets,
    int* __restrict__ cursor, int N) {
    __shared__ int sums[1024];
    int t = threadIdx.x;
    int per = (N + 1023) / 1024;
    int base = t * per;
    int s = 0;
    for (int j = 0; j < per; j++) {
        int idx = base + j;
        if (idx < N) s += counts[idx];
    }
    sums[t] = s;
    __syncthreads();
    int acc = s;
    for (int off = 1; off < 1024; off <<= 1) {
        int v = (t >= off) ? sums[t - off] : 0;
        __syncthreads();
        acc += v;
        sums[t] = acc;
        __syncthreads();
    }
    int run = acc - s;   // exclusive prefix of this thread's chunk
    for (int j = 0; j < per; j++) {
        int idx = base + j;
        if (idx < N) {
            offsets[idx] = run;
            cursor[idx] = run;
            run += counts[idx];
        }
    }
    if (t == 1023) offsets[N] = run;   // grand total
}

__global__ void fill_kernel(const int* __restrict__ ei, int* __restrict__ cursor,
                            int* __restrict__ srcs, int E, int N) {
    int i = blockIdx.x * blockDim.x + threadIdx.x;
    int M = E + N;
    if (i >= M) return;
    int src, dst;
    if (i < E) { src = ei[i]; dst = ei[E + i]; }
    else       { src = dst = i - E; }
    int pos = atomicAdd(&cursor[dst], 1);
    srcs[pos] = src;
}

// ---------------- Layer 1 transform: h1 = x @ W1, alpha_s/alpha_d ----------------
// 16 nodes per block, 256 threads. Thread owns 4 output channels (one head) x 16 nodes.

__global__ __launch_bounds__(256, 4) void l1_transform(
    const float* __restrict__ x, const float* __restrict__ W1,
    const float* __restrict__ a_src1, const float* __restrict__ a_dst1,
    float* __restrict__ h1, float* __restrict__ as1, float* __restrict__ ad1, int N) {
    int nb = blockIdx.x * 16;
    int t = threadIdx.x;
    __shared__ float xs[16 * 128];
#pragma unroll
    for (int r = 0; r < 2; r++) {
        int li = r * 1024 + t * 4;
        int node = nb + (li >> 7);
        float4 xv = make_float4(0.f, 0.f, 0.f, 0.f);
        if (node < N) xv = *(const float4*)(x + (size_t)nb * 128 + li);
        *(float4*)(xs + li) = xv;
    }
    __syncthreads();
    int c0 = t * 4;           // output channel 0..1023
    int h = t >> 5;           // head 0..7 (128 ch per head)
    float4 acc[16];
#pragma unroll
    for (int nd = 0; nd < 16; nd++) acc[nd] = make_float4(0.f, 0.f, 0.f, 0.f);
    for (int k = 0; k < 128; k++) {
        float4 w = *(const float4*)(W1 + (size_t)k * 1024 + c0);
#pragma unroll
        for (int nd = 0; nd < 16; nd++) {
            float xk = xs[nd * 128 + k];   // wave-uniform address -> LDS broadcast
            acc[nd].x = fmaf(xk, w.x, acc[nd].x);
            acc[nd].y = fmaf(xk, w.y, acc[nd].y);
            acc[nd].z = fmaf(xk, w.z, acc[nd].z);
            acc[nd].w = fmaf(xk, w.w, acc[nd].w);
        }
    }
    float4 asv = *(const float4*)(a_src1 + h * 128 + (c0 & 127));
    float4 adv = *(const float4*)(a_dst1 + h * 128 + (c0 & 127));
#pragma unroll
    for (int nd = 0; nd < 16; nd++) {
        int n = nb + nd;
        float4 a = acc[nd];
        float ps = a.x * asv.x + a.y * asv.y + a.z * asv.z + a.w * asv.w;
        float pd = a.x * adv.x + a.y * adv.y + a.z * adv.z + a.w * adv.w;
#pragma unroll
        for (int mm = 16; mm >= 1; mm >>= 1) {   // reduce across the 32 threads of this head
            ps += __shfl_xor(ps, mm);
            pd += __shfl_xor(pd, mm);
        }
        if (n < N) {
            *(float4*)(h1 + (size_t)n * 1024 + c0) = a;
            if ((t & 31) == 0) { as1[n * 8 + h] = ps; ad1[n * 8 + h] = pd; }
        }
    }
}

// ---------------- Layer 1 aggregate: segment softmax + weighted gather + bias + ELU ----
// Per dst node: phase A = per-head max; then chunks of 256 edges: stage srcs +
// softmax weights in LDS once, then pure gather+FMA accumulate.

#define CHUNK 256

__global__ __launch_bounds__(256) void l1_agg(
    const float* __restrict__ h1, const float* __restrict__ as1, const float* __restrict__ ad1,
    const float* __restrict__ b1, const int* __restrict__ offsets, const int* __restrict__ srcs,
    float* __restrict__ hbuf, int N) {
    int n = blockIdx.x;
    int t = threadIdx.x;
    int beg = offsets[n];
    int deg = offsets[n + 1] - beg;
    __shared__ int   ssrc[CHUNK];
    __shared__ float wsh[CHUNK * 8];
    __shared__ float ad[8], mh[8], sh[8];
    __shared__ float red[256];
    if (t < 8) ad[t] = ad1[n * 8 + t];
    __syncthreads();
    // --- phase A: per-head max over all incoming edges (8 heads x 32 edge-lanes) ---
    int h = t & 7, el = t >> 3;
    float m = -3.4e38f;
    for (int i = el; i < deg; i += 32) {
        int s = srcs[beg + i];
        m = fmaxf(m, leaky(as1[s * 8 + h] + ad[h]));
    }
    red[t] = m;
    __syncthreads();
    for (int off = 128; off >= 8; off >>= 1) {
        if (t < off) red[t] = fmaxf(red[t], red[t + off]);
        __syncthreads();
    }
    if (t < 8) mh[t] = red[t];
    __syncthreads();
    // --- chunked: stage srcs + weights, then accumulate ---
    int c0 = t * 4;
    int hh = t >> 5;
    float ax = 0.f, ay = 0.f, az = 0.f, aw = 0.f, ssum = 0.f;
    for (int cb = 0; cb < deg; cb += CHUNK) {
        int cd = min(CHUNK, deg - cb);
        if (t < cd) ssrc[t] = srcs[beg + cb + t];
        __syncthreads();
        for (int idx = t; idx < cd * 8; idx += 256) {
            int i = idx >> 3, hx = idx & 7;
            int s = ssrc[i];
            wsh[idx] = __expf(leaky(as1[s * 8 + hx] + ad[hx]) - mh[hx]);
        }
        __syncthreads();
        int i = 0;
        for (; i + 1 < cd; i += 2) {
            int s0 = ssrc[i], s1 = ssrc[i + 1];
            float w0 = wsh[i * 8 + hh], w1 = wsh[(i + 1) * 8 + hh];
            float4 v0 = *(const float4*)(h1 + (size_t)s0 * 1024 + c0);
            float4 v1 = *(const float4*)(h1 + (size_t)s1 * 1024 + c0);
            ax = fmaf(w0, v0.x, ax); ay = fmaf(w0, v0.y, ay);
            az = fmaf(w0, v0.z, az); aw = fmaf(w0, v0.w, aw);
            ax = fmaf(w1, v1.x, ax); ay = fmaf(w1, v1.y, ay);
            az = fmaf(w1, v1.z, az); aw = fmaf(w1, v1.w, aw);
            ssum += w0 + w1;
        }
        if (i < cd) {
            int s0 = ssrc[i];
            float w0 = wsh[i * 8 + hh];
            float4 v0 = *(const float4*)(h1 + (size_t)s0 * 1024 + c0);
            ax = fmaf(w0, v0.x, ax); ay = fmaf(w0, v0.y, ay);
            az = fmaf(w0, v0.z, az); aw = fmaf(w0, v0.w, aw);
            ssum += w0;
        }
        __syncthreads();
    }
    if ((t & 31) == 0) sh[hh] = ssum;   // t = 32*hh: participated in every iteration
    __syncthreads();
    float inv = 1.0f / (sh[hh] + 1e-16f);
    float4 bv = *(const float4*)(b1 + c0);
    float ox = ax * inv + bv.x;
    float oy = ay * inv + bv.y;
    float oz = az * inv + bv.z;
    float ow = aw * inv + bv.w;
    ox = ox > 0.f ? ox : expm1f(ox);
    oy = oy > 0.f ? oy : expm1f(oy);
    oz = oz > 0.f ? oz : expm1f(oz);
    ow = ow > 0.f ? ow : expm1f(ow);
    *(float4*)(hbuf + (size_t)n * 1024 + c0) = make_float4(ox, oy, oz, ow);
}

// ---------------- Layer 2 transform: h2 = hbuf @ W2, alpha_s2/alpha_d2 ----------------
// 8 nodes/block, 256 threads = 16 k-blocks x (16 threads x 4 channels).
// Single-sync LDS partial reduction, float4 W2 loads.

__global__ __launch_bounds__(256) void l2_transform(
    const float* __restrict__ hbuf, const float* __restrict__ W2,
    const float* __restrict__ a_src2, const float* __restrict__ a_dst2,
    float* __restrict__ h2, float* __restrict__ as2, float* __restrict__ ad2, int N) {
    int nb = blockIdx.x * 8;
    int t = threadIdx.x;
    __shared__ float hs[8 * 1024];     // 32 KB
    __shared__ float part[16 * 512];   // 32 KB
#pragma unroll
    for (int j = 0; j < 8; j++) {
        int idx = j * 1024 + t * 4;
        float4 v = make_float4(0.f, 0.f, 0.f, 0.f);
        if (nb + j < N) v = *(const float4*)(hbuf + (size_t)nb * 1024 + idx);
        *(float4*)(hs + idx) = v;
    }
    __syncthreads();
    int c0 = (t & 15) * 4, kb = t >> 4;   // 16 k-blocks of 64 k each
    float4 acc[8];
#pragma unroll
    for (int nd = 0; nd < 8; nd++) acc[nd] = make_float4(0.f, 0.f, 0.f, 0.f);
    int kbase = kb * 64;
    for (int j = 0; j < 64; j++) {
        int k = kbase + j;
        float4 w = *(const float4*)(W2 + (size_t)k * 64 + c0);
#pragma unroll
        for (int nd = 0; nd < 8; nd++) {
            float xk = hs[nd * 1024 + k];
            acc[nd].x = fmaf(xk, w.x, acc[nd].x);
            acc[nd].y = fmaf(xk, w.y, acc[nd].y);
            acc[nd].z = fmaf(xk, w.z, acc[nd].z);
            acc[nd].w = fmaf(xk, w.w, acc[nd].w);
        }
    }
#pragma unroll
    for (int nd = 0; nd < 8; nd++)
        *(float4*)(part + kb * 512 + nd * 64 + c0) = acc[nd];
    __syncthreads();
#pragma unroll
    for (int r = 0; r < 2; r++) {
        int oi = t + r * 256;            // nd*64 + c2, oi in [0,512)
        float v = 0.f;
#pragma unroll
        for (int k2 = 0; k2 < 16; k2++) v += part[k2 * 512 + oi];
        int nd = oi >> 6, c2 = t & 63;
        int n = nb + nd;
        float ps = v * a_src2[c2];
        float pd = v * a_dst2[c2];
#pragma unroll
        for (int mm = 32; mm >= 1; mm >>= 1) {   // node nd occupies exactly one wave
            ps += __shfl_xor(ps, mm);
            pd += __shfl_xor(pd, mm);
        }
        if (n < N) {
            h2[(size_t)n * 64 + c2] = v;
            if (c2 == 0) { as2[n] = ps; ad2[n] = pd; }
        }
    }
}

// ---------------- Layer 2 aggregate ----------------

__global__ __launch_bounds__(256) void l2_agg(
    const float* __restrict__ h2, const float* __restrict__ as2, const float* __restrict__ ad2,
    const float* __restrict__ b2, const int* __restrict__ offsets, const int* __restrict__ srcs,
    float* __restrict__ out, int N) {
    int n = blockIdx.x;
    int t = threadIdx.x;
    int beg = offsets[n];
    int deg = offsets[n + 1] - beg;
    __shared__ int   ssrc[CHUNK];
    __shared__ float wsh[CHUNK];
    __shared__ float red[256];
    __shared__ float m_sh, s_sh;
    float adn = ad2[n];
    float m = -3.4e38f;
    for (int i = t; i < deg; i += 256) m = fmaxf(m, leaky(as2[srcs[beg + i]] + adn));
    red[t] = m;
    __syncthreads();
    for (int off = 128; off >= 1; off >>= 1) {
        if (t < off) red[t] = fmaxf(red[t], red[t + off]);
        __syncthreads();
    }
    if (t == 0) m_sh = red[0];
    __syncthreads();
    float mv = m_sh;
    int c = t & 63, eg = t >> 6;
    float acc = 0.f, wpart = 0.f;
    for (int cb = 0; cb < deg; cb += CHUNK) {
        int cd = min(CHUNK, deg - cb);
        if (t < cd) {
            int s = srcs[beg + cb + t];
            ssrc[t] = s;
            float w = __expf(leaky(as2[s] + adn) - mv);
            wsh[t] = w;
            wpart += w;
        }
        __syncthreads();
        for (int i = eg; i < cd; i += 4)
            acc = fmaf(wsh[i], h2[(size_t)ssrc[i] * 64 + c], acc);
        __syncthreads();
    }
    red[t] = wpart;
    __syncthreads();
    for (int off = 128; off >= 1; off >>= 1) {
        if (t < off) red[t] += red[t + off];
        __syncthreads();
    }
    if (t == 0) s_sh = red[0] + 1e-16f;
    __syncthreads();
    float stot = s_sh;
    red[t] = acc;
    __syncthreads();
    if (t < 128) red[t] += red[t + 128];
    __syncthreads();
    if (t < 64) {
        float v = red[t] + red[t + 64];
        out[(size_t)n * 64 + t] = v / stot + b2[t];
    }
}

// ---------------- launch ----------------

static inline size_t align_up(size_t v, size_t a) { return (v + a - 1) / a * a; }

extern "C" void kernel_launch(void* const* d_in, const int* in_sizes, int n_in,
                              void* d_out, int out_size, void* d_ws, size_t ws_size,
                              hipStream_t stream) {
    const float* x      = (const float*)d_in[0];
    const int*   ei     = (const int*)d_in[1];
    const float* W1     = (const float*)d_in[2];
    const float* a_src1 = (const float*)d_in[3];
    const float* a_dst1 = (const float*)d_in[4];
    const float* b1     = (const float*)d_in[5];
    const float* W2     = (const float*)d_in[6];
    const float* a_src2 = (const float*)d_in[7];
    const float* a_dst2 = (const float*)d_in[8];
    const float* b2     = (const float*)d_in[9];
    float* out = (float*)d_out;

    int N = in_sizes[0] / 128;
    int E = in_sizes[1] / 2;
    int M = E + N;

    char* p = (char*)d_ws;
    size_t off = 0;
    auto carve = [&](size_t bytes) {
        void* r = p + off;
        off = align_up(off + bytes, 256);
        return r;
    };
    int*   counts  = (int*)carve((size_t)N * 4);
    int*   offsets = (int*)carve((size_t)(N + 1) * 4);
    int*   cursor  = (int*)carve((size_t)N * 4);
    int*   srcs    = (int*)carve((size_t)M * 4);
    float* as1     = (float*)carve((size_t)N * 8 * 4);
    float* ad1     = (float*)carve((size_t)N * 8 * 4);
    float* as2     = (float*)carve((size_t)N * 4);
    float* ad2     = (float*)carve((size_t)N * 4);
    float* h2      = (float*)carve((size_t)N * 64 * 4);
    float* h1      = (float*)carve((size_t)N * 1024 * 4);
    float* hbuf    = (float*)carve((size_t)N * 1024 * 4);
    (void)ws_size; // needs ~86 MB

    hipMemsetAsync(counts, 0, (size_t)N * 4, stream);
    count_kernel<<<(M + 255) / 256, 256, 0, stream>>>(ei, counts, E, N);
    scan_kernel<<<1, 1024, 0, stream>>>(counts, offsets, cursor, N);
    fill_kernel<<<(M + 255) / 256, 256, 0, stream>>>(ei, cursor, srcs, E, N);
    l1_transform<<<(N + 15) / 16, 256, 0, stream>>>(x, W1, a_src1, a_dst1, h1, as1, ad1, N);
    l1_agg<<<N, 256, 0, stream>>>(h1, as1, ad1, b1, offsets, srcs, hbuf, N);
    l2_transform<<<(N + 7) / 8, 256, 0, stream>>>(hbuf, W2, a_src2, a_dst2, h2, as2, ad2, N);
    l2_agg<<<N, 256, 0, stream>>>(h2, as2, ad2, b2, offsets, srcs, out, N);
}

// Round 3
// 281.506 us; speedup vs baseline: 1.1621x; 1.0684x over previous
//
#include <hip/hip_runtime.h>
#include <math.h>

// GAT 2-layer: N=10000, E=160000 (+N self loops), IN=128, H1=8, C1=128, OUT=64.
// R3: layer-1 uses associativity  A@(x@W1) = (A@x)@W1 :
//   - prep:    As = W1 . a_src1 per head (128x8), Ad likewise
//   - alpha1:  as1/ad1 = x @ As / Ad              (logits, exact algebra)
//   - l1_aggx: y[n,h,:] = softmax-weighted sum of x[src,:]   (512B/edge gather,
//              8x less than gathering h1 rows; x is 5MB -> L2-resident)
//   - l1_gemm: hbuf[n, h*128+c] = ELU(y[n,h,:] @ W1[:, h*128+c] + b1)
// Layer 2 keeps transform-then-aggregate (IN=1024 > OUT=64).

#define NEG_SLOPE 0.2f

__device__ __forceinline__ float leaky(float v) { return v >= 0.0f ? v : NEG_SLOPE * v; }

// ---------------- CSR build ----------------

__global__ void count_kernel(const int* __restrict__ ei, int* __restrict__ counts, int E, int N) {
    int i = blockIdx.x * blockDim.x + threadIdx.x;
    int M = E + N;
    if (i >= M) return;
    int dst = (i < E) ? ei[E + i] : (i - E);   // self-loop tail
    atomicAdd(&counts[dst], 1);
}

__global__ __launch_bounds__(1024) void scan_kernel(
    const int* __restrict__ counts, int* __restrict__ offsets,
    int* __restrict__ cursor, int N) {
    __shared__ int sums[1024];
    int t = threadIdx.x;
    int per = (N + 1023) / 1024;
    int base = t * per;
    int s = 0;
    for (int j = 0; j < per; j++) {
        int idx = base + j;
        if (idx < N) s += counts[idx];
    }
    sums[t] = s;
    __syncthreads();
    int acc = s;
    for (int off = 1; off < 1024; off <<= 1) {
        int v = (t >= off) ? sums[t - off] : 0;
        __syncthreads();
        acc += v;
        sums[t] = acc;
        __syncthreads();
    }
    int run = acc - s;
    for (int j = 0; j < per; j++) {
        int idx = base + j;
        if (idx < N) {
            offsets[idx] = run;
            cursor[idx] = run;
            run += counts[idx];
        }
    }
    if (t == 1023) offsets[N] = run;
}

__global__ void fill_kernel(const int* __restrict__ ei, int* __restrict__ cursor,
                            int* __restrict__ srcs, int E, int N) {
    int i = blockIdx.x * blockDim.x + threadIdx.x;
    int M = E + N;
    if (i >= M) return;
    int src, dst;
    if (i < E) { src = ei[i]; dst = ei[E + i]; }
    else       { src = dst = i - E; }
    int pos = atomicAdd(&cursor[dst], 1);
    srcs[pos] = src;
}

// ---------------- prep: As[k,h] = sum_c W1[k,h*128+c]*a_src1[h,c]  (and Ad) ----

__global__ __launch_bounds__(256) void prep_kernel(
    const float* __restrict__ W1, const float* __restrict__ a_src1,
    const float* __restrict__ a_dst1, float* __restrict__ As, float* __restrict__ Ad) {
    int i = blockIdx.x * 256 + threadIdx.x;   // 0..1023
    int k = i >> 3, h = i & 7;
    float ss = 0.f, sd = 0.f;
    for (int c = 0; c < 128; c += 4) {
        float4 w = *(const float4*)(W1 + (size_t)k * 1024 + h * 128 + c);
        float4 a = *(const float4*)(a_src1 + h * 128 + c);
        float4 d = *(const float4*)(a_dst1 + h * 128 + c);
        ss += w.x * a.x + w.y * a.y + w.z * a.z + w.w * a.w;
        sd += w.x * d.x + w.y * d.y + w.z * d.z + w.w * d.w;
    }
    As[k * 8 + h] = ss;
    Ad[k * 8 + h] = sd;
}

// ---------------- alpha1: as1/ad1 = x @ As / Ad  [N,8] ----------------
// 32 nodes/block; thread = (local node, head).

__global__ __launch_bounds__(256) void alpha1_kernel(
    const float* __restrict__ x, const float* __restrict__ As, const float* __restrict__ Ad,
    float* __restrict__ as1, float* __restrict__ ad1, int N) {
    __shared__ float sAs[1024], sAd[1024];
    int t = threadIdx.x;
    {
        int i = t * 4;
        *(float4*)(sAs + i) = *(const float4*)(As + i);
        *(float4*)(sAd + i) = *(const float4*)(Ad + i);
    }
    __syncthreads();
    int node = blockIdx.x * 32 + (t >> 3);
    int h = t & 7;
    if (node >= N) return;
    float accs = 0.f, accd = 0.f;
    for (int k = 0; k < 128; k += 4) {
        float4 xv = *(const float4*)(x + (size_t)node * 128 + k);
        accs += xv.x * sAs[k * 8 + h] + xv.y * sAs[(k + 1) * 8 + h]
              + xv.z * sAs[(k + 2) * 8 + h] + xv.w * sAs[(k + 3) * 8 + h];
        accd += xv.x * sAd[k * 8 + h] + xv.y * sAd[(k + 1) * 8 + h]
              + xv.z * sAd[(k + 2) * 8 + h] + xv.w * sAd[(k + 3) * 8 + h];
    }
    as1[node * 8 + h] = accs;
    ad1[node * 8 + h] = accd;
}

// ---------------- l1_aggx: y[n,h,:] = sum_e softmax-w * x[src,:] -----------
// One block per dst node. Thread: head h = t>>5, channels k0 = (t&31)*4.

#define CHUNK 256

__global__ __launch_bounds__(256) void l1_aggx(
    const float* __restrict__ x, const float* __restrict__ as1, const float* __restrict__ ad1,
    const int* __restrict__ offsets, const int* __restrict__ srcs,
    float* __restrict__ y, int N) {
    int n = blockIdx.x;
    int t = threadIdx.x;
    int beg = offsets[n];
    int deg = offsets[n + 1] - beg;
    __shared__ int   ssrc[CHUNK];
    __shared__ float wsh[CHUNK * 8];
    __shared__ float ad[8], mh[8];
    __shared__ float red[256];
    if (t < 8) ad[t] = ad1[n * 8 + t];
    __syncthreads();
    // phase A: per-head max (8 heads x 32 edge-lanes)
    int h8 = t & 7, el = t >> 3;
    float m = -3.4e38f;
    for (int i = el; i < deg; i += 32) {
        int s = srcs[beg + i];
        m = fmaxf(m, leaky(as1[s * 8 + h8] + ad[h8]));
    }
    red[t] = m;
    __syncthreads();
    for (int off = 128; off >= 8; off >>= 1) {
        if (t < off) red[t] = fmaxf(red[t], red[t + off]);
        __syncthreads();
    }
    if (t < 8) mh[t] = red[t];
    __syncthreads();
    // phase B: chunked softmax-weight staging + x-row gather accumulate
    int h = t >> 5;
    int k0 = (t & 31) * 4;
    float ax = 0.f, ay = 0.f, az = 0.f, aw = 0.f, ssum = 0.f;
    for (int cb = 0; cb < deg; cb += CHUNK) {
        int cd = min(CHUNK, deg - cb);
        if (t < cd) ssrc[t] = srcs[beg + cb + t];
        __syncthreads();
        for (int idx = t; idx < cd * 8; idx += 256) {
            int i = idx >> 3, hx = idx & 7;
            int s = ssrc[i];
            wsh[idx] = __expf(leaky(as1[s * 8 + hx] + ad[hx]) - mh[hx]);
        }
        __syncthreads();
        int i = 0;
        for (; i + 1 < cd; i += 2) {
            int s0 = ssrc[i], s1 = ssrc[i + 1];
            float w0 = wsh[i * 8 + h], w1 = wsh[(i + 1) * 8 + h];
            float4 v0 = *(const float4*)(x + (size_t)s0 * 128 + k0);
            float4 v1 = *(const float4*)(x + (size_t)s1 * 128 + k0);
            ax = fmaf(w0, v0.x, ax); ay = fmaf(w0, v0.y, ay);
            az = fmaf(w0, v0.z, az); aw = fmaf(w0, v0.w, aw);
            ax = fmaf(w1, v1.x, ax); ay = fmaf(w1, v1.y, ay);
            az = fmaf(w1, v1.z, az); aw = fmaf(w1, v1.w, aw);
            ssum += w0 + w1;
        }
        if (i < cd) {
            int s0 = ssrc[i];
            float w0 = wsh[i * 8 + h];
            float4 v0 = *(const float4*)(x + (size_t)s0 * 128 + k0);
            ax = fmaf(w0, v0.x, ax); ay = fmaf(w0, v0.y, ay);
            az = fmaf(w0, v0.z, az); aw = fmaf(w0, v0.w, aw);
            ssum += w0;
        }
        __syncthreads();
    }
    // every thread iterated all edges -> ssum is the full per-head sum
    float inv = 1.0f / (ssum + 1e-16f);
    // y layout [n][h*128 + k] ; h*128 + k0 == t*4
    *(float4*)(y + (size_t)n * 1024 + t * 4) =
        make_float4(ax * inv, ay * inv, az * inv, aw * inv);
}

// ---------------- l1_gemm: hbuf = ELU(per-head y @ W1 + b1) ----------------
// 16 nodes/block, 256 threads; thread owns output channels c0=t*4 (head t>>5).

__global__ __launch_bounds__(256, 2) void l1_gemm(
    const float* __restrict__ y, const float* __restrict__ W1,
    const float* __restrict__ b1, float* __restrict__ hbuf, int N) {
    int nb = blockIdx.x * 16;
    int t = threadIdx.x;
    __shared__ float ys[16 * 1024];   // 64 KB
#pragma unroll
    for (int r = 0; r < 16; r++) {
        int idx = r * 1024 + t * 4;
        int node = nb + r;
        float4 v = make_float4(0.f, 0.f, 0.f, 0.f);
        if (node < N) v = *(const float4*)(y + (size_t)nb * 1024 + idx);
        *(float4*)(ys + idx) = v;
    }
    __syncthreads();
    int c0 = t * 4;
    int h = t >> 5;
    float4 acc[16];
#pragma unroll
    for (int nd = 0; nd < 16; nd++) acc[nd] = make_float4(0.f, 0.f, 0.f, 0.f);
    for (int k = 0; k < 128; k += 4) {
        float4 w0 = *(const float4*)(W1 + (size_t)(k + 0) * 1024 + c0);
        float4 w1 = *(const float4*)(W1 + (size_t)(k + 1) * 1024 + c0);
        float4 w2 = *(const float4*)(W1 + (size_t)(k + 2) * 1024 + c0);
        float4 w3 = *(const float4*)(W1 + (size_t)(k + 3) * 1024 + c0);
#pragma unroll
        for (int nd = 0; nd < 16; nd++) {
            float4 yv = *(const float4*)(ys + nd * 1024 + h * 128 + k);
            acc[nd].x = fmaf(yv.x, w0.x, acc[nd].x);
            acc[nd].y = fmaf(yv.x, w0.y, acc[nd].y);
            acc[nd].z = fmaf(yv.x, w0.z, acc[nd].z);
            acc[nd].w = fmaf(yv.x, w0.w, acc[nd].w);
            acc[nd].x = fmaf(yv.y, w1.x, acc[nd].x);
            acc[nd].y = fmaf(yv.y, w1.y, acc[nd].y);
            acc[nd].z = fmaf(yv.y, w1.z, acc[nd].z);
            acc[nd].w = fmaf(yv.y, w1.w, acc[nd].w);
            acc[nd].x = fmaf(yv.z, w2.x, acc[nd].x);
            acc[nd].y = fmaf(yv.z, w2.y, acc[nd].y);
            acc[nd].z = fmaf(yv.z, w2.z, acc[nd].z);
            acc[nd].w = fmaf(yv.z, w2.w, acc[nd].w);
            acc[nd].x = fmaf(yv.w, w3.x, acc[nd].x);
            acc[nd].y = fmaf(yv.w, w3.y, acc[nd].y);
            acc[nd].z = fmaf(yv.w, w3.z, acc[nd].z);
            acc[nd].w = fmaf(yv.w, w3.w, acc[nd].w);
        }
    }
    float4 bv = *(const float4*)(b1 + c0);
#pragma unroll
    for (int nd = 0; nd < 16; nd++) {
        int n = nb + nd;
        if (n >= N) break;
        float ox = acc[nd].x + bv.x;
        float oy = acc[nd].y + bv.y;
        float oz = acc[nd].z + bv.z;
        float ow = acc[nd].w + bv.w;
        ox = ox > 0.f ? ox : expm1f(ox);
        oy = oy > 0.f ? oy : expm1f(oy);
        oz = oz > 0.f ? oz : expm1f(oz);
        ow = ow > 0.f ? ow : expm1f(ow);
        *(float4*)(hbuf + (size_t)n * 1024 + c0) = make_float4(ox, oy, oz, ow);
    }
}

// ---------------- Layer 2 transform: h2 = hbuf @ W2, alpha_s2/alpha_d2 ------

__global__ __launch_bounds__(256) void l2_transform(
    const float* __restrict__ hbuf, const float* __restrict__ W2,
    const float* __restrict__ a_src2, const float* __restrict__ a_dst2,
    float* __restrict__ h2, float* __restrict__ as2, float* __restrict__ ad2, int N) {
    int nb = blockIdx.x * 8;
    int t = threadIdx.x;
    __shared__ float hs[8 * 1024];     // 32 KB
    __shared__ float part[16 * 512];   // 32 KB
#pragma unroll
    for (int j = 0; j < 8; j++) {
        int idx = j * 1024 + t * 4;
        float4 v = make_float4(0.f, 0.f, 0.f, 0.f);
        if (nb + j < N) v = *(const float4*)(hbuf + (size_t)nb * 1024 + idx);
        *(float4*)(hs + idx) = v;
    }
    __syncthreads();
    int c0 = (t & 15) * 4, kb = t >> 4;
    float4 acc[8];
#pragma unroll
    for (int nd = 0; nd < 8; nd++) acc[nd] = make_float4(0.f, 0.f, 0.f, 0.f);
    int kbase = kb * 64;
    for (int j = 0; j < 64; j++) {
        int k = kbase + j;
        float4 w = *(const float4*)(W2 + (size_t)k * 64 + c0);
#pragma unroll
        for (int nd = 0; nd < 8; nd++) {
            float xk = hs[nd * 1024 + k];
            acc[nd].x = fmaf(xk, w.x, acc[nd].x);
            acc[nd].y = fmaf(xk, w.y, acc[nd].y);
            acc[nd].z = fmaf(xk, w.z, acc[nd].z);
            acc[nd].w = fmaf(xk, w.w, acc[nd].w);
        }
    }
#pragma unroll
    for (int nd = 0; nd < 8; nd++)
        *(float4*)(part + kb * 512 + nd * 64 + c0) = acc[nd];
    __syncthreads();
#pragma unroll
    for (int r = 0; r < 2; r++) {
        int oi = t + r * 256;
        float v = 0.f;
#pragma unroll
        for (int k2 = 0; k2 < 16; k2++) v += part[k2 * 512 + oi];
        int nd = oi >> 6, c2 = t & 63;
        int n = nb + nd;
        float ps = v * a_src2[c2];
        float pd = v * a_dst2[c2];
#pragma unroll
        for (int mm = 32; mm >= 1; mm >>= 1) {
            ps += __shfl_xor(ps, mm);
            pd += __shfl_xor(pd, mm);
        }
        if (n < N) {
            h2[(size_t)n * 64 + c2] = v;
            if (c2 == 0) { as2[n] = ps; ad2[n] = pd; }
        }
    }
}

// ---------------- Layer 2 aggregate ----------------

__global__ __launch_bounds__(256) void l2_agg(
    const float* __restrict__ h2, const float* __restrict__ as2, const float* __restrict__ ad2,
    const float* __restrict__ b2, const int* __restrict__ offsets, const int* __restrict__ srcs,
    float* __restrict__ out, int N) {
    int n = blockIdx.x;
    int t = threadIdx.x;
    int beg = offsets[n];
    int deg = offsets[n + 1] - beg;
    __shared__ int   ssrc[CHUNK];
    __shared__ float wsh[CHUNK];
    __shared__ float red[256];
    __shared__ float m_sh, s_sh;
    float adn = ad2[n];
    float m = -3.4e38f;
    for (int i = t; i < deg; i += 256) m = fmaxf(m, leaky(as2[srcs[beg + i]] + adn));
    red[t] = m;
    __syncthreads();
    for (int off = 128; off >= 1; off >>= 1) {
        if (t < off) red[t] = fmaxf(red[t], red[t + off]);
        __syncthreads();
    }
    if (t == 0) m_sh = red[0];
    __syncthreads();
    float mv = m_sh;
    int c = t & 63, eg = t >> 6;
    float acc = 0.f, wpart = 0.f;
    for (int cb = 0; cb < deg; cb += CHUNK) {
        int cd = min(CHUNK, deg - cb);
        if (t < cd) {
            int s = srcs[beg + cb + t];
            ssrc[t] = s;
            float w = __expf(leaky(as2[s] + adn) - mv);
            wsh[t] = w;
            wpart += w;
        }
        __syncthreads();
        for (int i = eg; i < cd; i += 4)
            acc = fmaf(wsh[i], h2[(size_t)ssrc[i] * 64 + c], acc);
        __syncthreads();
    }
    red[t] = wpart;
    __syncthreads();
    for (int off = 128; off >= 1; off >>= 1) {
        if (t < off) red[t] += red[t + off];
        __syncthreads();
    }
    if (t == 0) s_sh = red[0] + 1e-16f;
    __syncthreads();
    float stot = s_sh;
    red[t] = acc;
    __syncthreads();
    if (t < 128) red[t] += red[t + 128];
    __syncthreads();
    if (t < 64) {
        float v = red[t] + red[t + 64];
        out[(size_t)n * 64 + t] = v / stot + b2[t];
    }
}

// ---------------- launch ----------------

static inline size_t align_up(size_t v, size_t a) { return (v + a - 1) / a * a; }

extern "C" void kernel_launch(void* const* d_in, const int* in_sizes, int n_in,
                              void* d_out, int out_size, void* d_ws, size_t ws_size,
                              hipStream_t stream) {
    const float* x      = (const float*)d_in[0];
    const int*   ei     = (const int*)d_in[1];
    const float* W1     = (const float*)d_in[2];
    const float* a_src1 = (const float*)d_in[3];
    const float* a_dst1 = (const float*)d_in[4];
    const float* b1     = (const float*)d_in[5];
    const float* W2     = (const float*)d_in[6];
    const float* a_src2 = (const float*)d_in[7];
    const float* a_dst2 = (const float*)d_in[8];
    const float* b2     = (const float*)d_in[9];
    float* out = (float*)d_out;

    int N = in_sizes[0] / 128;
    int E = in_sizes[1] / 2;
    int M = E + N;

    char* p = (char*)d_ws;
    size_t off = 0;
    auto carve = [&](size_t bytes) {
        void* r = p + off;
        off = align_up(off + bytes, 256);
        return r;
    };
    int*   counts  = (int*)carve((size_t)N * 4);
    int*   offsets = (int*)carve((size_t)(N + 1) * 4);
    int*   cursor  = (int*)carve((size_t)N * 4);
    int*   srcs    = (int*)carve((size_t)M * 4);
    float* As      = (float*)carve(1024 * 4);
    float* Ad      = (float*)carve(1024 * 4);
    float* as1     = (float*)carve((size_t)N * 8 * 4);
    float* ad1     = (float*)carve((size_t)N * 8 * 4);
    float* as2     = (float*)carve((size_t)N * 4);
    float* ad2     = (float*)carve((size_t)N * 4);
    float* h2      = (float*)carve((size_t)N * 64 * 4);
    float* y       = (float*)carve((size_t)N * 1024 * 4);
    float* hbuf    = (float*)carve((size_t)N * 1024 * 4);
    (void)ws_size; // ~86 MB

    hipMemsetAsync(counts, 0, (size_t)N * 4, stream);
    prep_kernel<<<4, 256, 0, stream>>>(W1, a_src1, a_dst1, As, Ad);
    alpha1_kernel<<<(N + 31) / 32, 256, 0, stream>>>(x, As, Ad, as1, ad1, N);
    count_kernel<<<(M + 255) / 256, 256, 0, stream>>>(ei, counts, E, N);
    scan_kernel<<<1, 1024, 0, stream>>>(counts, offsets, cursor, N);
    fill_kernel<<<(M + 255) / 256, 256, 0, stream>>>(ei, cursor, srcs, E, N);
    l1_aggx<<<N, 256, 0, stream>>>(x, as1, ad1, offsets, srcs, y, N);
    l1_gemm<<<(N + 15) / 16, 256, 0, stream>>>(y, W1, b1, hbuf, N);
    l2_transform<<<(N + 7) / 8, 256, 0, stream>>>(hbuf, W2, a_src2, a_dst2, h2, as2, ad2, N);
    l2_agg<<<N, 256, 0, stream>>>(h2, as2, ad2, b2, offsets, srcs, out, N);
}